// Round 3
// baseline (323.438 us; speedup 1.0000x reference)
//
#include <hip/hip_runtime.h>

#define NSRC 20000
#define NDST 20000
#define NTOT 40000
#define ETOT 320000
#define ENEG 316800
#define NH 8
#define ND 16
#define NHD 128
#define NBLK_AGG (NDST / 4)

// ---------------- workspace layout (bytes) ----------------
// [0, 64)            donecnt (u32)                    } zeroed
// [64, 320)          partial[64] (f32)                } zeroed
// [512, 80512)       count   (20000 int)              } zeroed
// [80512, 160512)    cursor  (20000 int)              } zeroed
// [160512, 480512)   flag    (320000 u8)              } zeroed -> zero region 480512 B
// [480512, 560576)   rowstart (20001 int, padded)
// [560576, 1840576)  csr (320000 int; bit31 = in-neg-set)
// [1840576, 22320576) z (40000 x 128 f32)
// [22320576, 23600576) el (40000 x 8 f32)
// [23600576, 24880576) er (40000 x 8 f32)

// GEMM z = feat @ fc_w with fused el/er epilogue; extra blocks do hist+flag.
// Grid (2, 689): by<625 -> gemm tile (64 rows x 64 cols); by>=625 -> 128 blocks
// of edge histogram + neg-flag scatter (independent work, overlapped).
__global__ __launch_bounds__(256) void k_front(const float* __restrict__ A,
                                               const float* __restrict__ B,
                                               const float* __restrict__ attn_l,
                                               const float* __restrict__ attn_r,
                                               const int* __restrict__ edge_dst,
                                               const int* __restrict__ neg_idx,
                                               float* __restrict__ C,
                                               float* __restrict__ el,
                                               float* __restrict__ er,
                                               int* __restrict__ count,
                                               unsigned char* __restrict__ flag) {
    const int tid = threadIdx.x;
    const int bx = blockIdx.x, by = blockIdx.y;
    if (by >= 625) {  // ---- hist + flag blocks ----
        int t0 = ((by - 625) * 2 + bx) * 256 + tid;  // 0..32767
        for (int i = t0; i < ETOT; i += 32768)
            atomicAdd(&count[edge_dst[i] - NSRC], 1);
        for (int i = t0; i < ENEG; i += 32768) flag[neg_idx[i]] = 1;
        return;
    }
    __shared__ float As[16][64];  // [k][m]
    __shared__ float Bs[16][64];  // [k][n]
    const int tx = tid & 15, ty = tid >> 4;
    const int row0 = by * 64 + ty * 4;
    const int col0 = bx * 64 + tx * 4;
    const int lr = tid >> 2, ls = tid & 3;
    const int br = tid >> 4, bs = tid & 15;
    float acc[4][4] = {};
    for (int k0 = 0; k0 < 128; k0 += 16) {
        float4 av = *(const float4*)(A + (by * 64 + lr) * 128 + k0 + ls * 4);
        float4 bv = *(const float4*)(B + (k0 + br) * 128 + bx * 64 + bs * 4);
        __syncthreads();
        As[ls * 4 + 0][lr] = av.x;
        As[ls * 4 + 1][lr] = av.y;
        As[ls * 4 + 2][lr] = av.z;
        As[ls * 4 + 3][lr] = av.w;
        *(float4*)(&Bs[br][bs * 4]) = bv;
        __syncthreads();
#pragma unroll
        for (int k = 0; k < 16; ++k) {
            float4 a = *(const float4*)(&As[k][ty * 4]);
            float4 b = *(const float4*)(&Bs[k][tx * 4]);
            acc[0][0] = fmaf(a.x, b.x, acc[0][0]);
            acc[0][1] = fmaf(a.x, b.y, acc[0][1]);
            acc[0][2] = fmaf(a.x, b.z, acc[0][2]);
            acc[0][3] = fmaf(a.x, b.w, acc[0][3]);
            acc[1][0] = fmaf(a.y, b.x, acc[1][0]);
            acc[1][1] = fmaf(a.y, b.y, acc[1][1]);
            acc[1][2] = fmaf(a.y, b.z, acc[1][2]);
            acc[1][3] = fmaf(a.y, b.w, acc[1][3]);
            acc[2][0] = fmaf(a.z, b.x, acc[2][0]);
            acc[2][1] = fmaf(a.z, b.y, acc[2][1]);
            acc[2][2] = fmaf(a.z, b.z, acc[2][2]);
            acc[2][3] = fmaf(a.z, b.w, acc[2][3]);
            acc[3][0] = fmaf(a.w, b.x, acc[3][0]);
            acc[3][1] = fmaf(a.w, b.y, acc[3][1]);
            acc[3][2] = fmaf(a.w, b.z, acc[3][2]);
            acc[3][3] = fmaf(a.w, b.w, acc[3][3]);
        }
    }
#pragma unroll
    for (int i = 0; i < 4; ++i) {
        *(float4*)(C + (row0 + i) * 128 + col0) =
            make_float4(acc[i][0], acc[i][1], acc[i][2], acc[i][3]);
    }
    // ---- fused el/er epilogue ----
    // head hh = bx*4 + tx/4 occupies local cols (tx/4)*16..+15; this thread's
    // 4 cols are d = (tx&3)*4 .. +3 within that head.
    const int hh = bx * 4 + (tx >> 2);
    const int q = tx & 3;
    float4 lv = *(const float4*)(attn_l + hh * ND + q * 4);
    float4 rv = *(const float4*)(attn_r + hh * ND + q * 4);
    float pl[4], pr[4];
#pragma unroll
    for (int i = 0; i < 4; ++i) {
        pl[i] = acc[i][0] * lv.x + acc[i][1] * lv.y + acc[i][2] * lv.z + acc[i][3] * lv.w;
        pr[i] = acc[i][0] * rv.x + acc[i][1] * rv.y + acc[i][2] * rv.z + acc[i][3] * rv.w;
    }
    // reduce over q (lane bits 0..1 within the wave)
#pragma unroll
    for (int s = 1; s <= 2; s <<= 1) {
#pragma unroll
        for (int i = 0; i < 4; ++i) {
            pl[i] += __shfl_xor(pl[i], s, 64);
            pr[i] += __shfl_xor(pr[i], s, 64);
        }
    }
    if (q == 0) {
#pragma unroll
        for (int i = 0; i < 4; ++i) {
            el[(row0 + i) * NH + hh] = pl[i];
            er[(row0 + i) * NH + hh] = pr[i];
        }
    }
}

// single-block scan: each thread owns 20 contiguous counts, shfl block scan
__global__ __launch_bounds__(1024) void k_scan(const int* __restrict__ count,
                                               int* __restrict__ rowstart) {
    __shared__ int wsum[16];
    const int tid = threadIdx.x;
    const int lane = tid & 63, w = tid >> 6;
    const int base = tid * 20;
    int c[20];
    int s = 0;
#pragma unroll
    for (int k = 0; k < 20; ++k) {
        int i = base + k;
        int v = (i < NDST) ? count[i] : 0;
        c[k] = s;
        s += v;
    }
    int v = s;
    for (int sh = 1; sh < 64; sh <<= 1) {
        int t = __shfl_up(v, sh, 64);
        if (lane >= sh) v += t;
    }
    if (lane == 63) wsum[w] = v;
    __syncthreads();
    int carry = 0;
    for (int ww = 0; ww < w; ++ww) carry += wsum[ww];
    int excl = carry + v - s;
#pragma unroll
    for (int k = 0; k < 20; ++k) {
        int i = base + k;
        if (i < NDST) rowstart[i] = excl + c[k];
    }
    if (tid == 1023) rowstart[NDST] = carry + v;  // = ETOT
}

__global__ __launch_bounds__(256) void k_scatter(const int* __restrict__ edge_src,
                                                 const int* __restrict__ edge_dst,
                                                 const unsigned char* __restrict__ flag,
                                                 const int* __restrict__ rowstart,
                                                 int* __restrict__ cursor,
                                                 int* __restrict__ csr) {
    int i = blockIdx.x * 256 + threadIdx.x;
    if (i >= ETOT) return;
    int d = edge_dst[i] - NSRC;
    int pos = rowstart[d] + atomicAdd(&cursor[d], 1);
    int v = edge_src[i];
    if (flag[i]) v |= (int)0x80000000u;
    csr[pos] = v;
}

// One wave per dst node, chunk = 16 edges. Fused loss tail via two-level
// atomics + last-block reduction (agent-scope acquire for cross-XCD safety).
__global__ __launch_bounds__(256) void k_agg(const int* __restrict__ rowstart,
                                             const int* __restrict__ csr,
                                             const float* __restrict__ z,
                                             const float* __restrict__ el,
                                             const float* __restrict__ er,
                                             const float* __restrict__ bias,
                                             const float* __restrict__ prelu_a,
                                             float* __restrict__ out,
                                             float* __restrict__ partial,
                                             unsigned int* __restrict__ donecnt) {
    const int lane = threadIdx.x & 63;
    const int wid = threadIdx.x >> 6;
    const int d = (blockIdx.x << 2) + wid;  // grid = NDST/4 exactly

    const int g = NSRC + d;
    const int hl = lane >> 3;
    const int j8 = lane & 7;
    const float erd = er[g * NH + hl];
    const float aslope = prelu_a[0];
    const float NEGINF = -__builtin_inff();
    __shared__ float sacc[4];

    float mF = NEGINF, lF = 0.f, mN = NEGINF, lN = 0.f;
    float aF0 = 0.f, aF1 = 0.f, aN0 = 0.f, aN1 = 0.f;
    const int rs = rowstart[d];
    const int deg = rowstart[d + 1] - rs;

    for (int base = 0; base < deg; base += 16) {
        const int j0 = base + j8, j1 = base + 8 + j8;
        int ent0 = (j0 < deg) ? csr[rs + j0] : g;
        int ent1 = (j1 < deg) ? csr[rs + j1] : g;
        float2 zr[16];
#pragma unroll
        for (int jj = 0; jj < 16; ++jj) {
            int entry = __shfl((jj < 8) ? ent0 : ent1, jj & 7, 64);
            const float* zp = z + (size_t)(entry & 0x7FFFFFFF) * NHD + 2 * lane;
            zr[jj] = *(const float2*)zp;
        }
        float e0 = el[(size_t)(ent0 & 0x7FFFFFFF) * NH + hl] + erd;
        float e1 = el[(size_t)(ent1 & 0x7FFFFFFF) * NH + hl] + erd;
        e0 = (e0 >= 0.f) ? e0 : 0.2f * e0;
        e1 = (e1 >= 0.f) ? e1 : 0.2f * e1;
        float ev0 = (j0 < deg) ? e0 : NEGINF;
        float ev1 = (j1 < deg) ? e1 : NEGINF;
        const int fl0 = (j0 < deg) && (ent0 < 0);
        const int fl1 = (j1 < deg) && (ent1 < 0);
        float cmF = fmaxf(ev0, ev1);
        float cmN = fmaxf(fl0 ? ev0 : NEGINF, fl1 ? ev1 : NEGINF);
#pragma unroll
        for (int s = 1; s <= 4; s <<= 1) {
            cmF = fmaxf(cmF, __shfl_xor(cmF, s, 64));
            cmN = fmaxf(cmN, __shfl_xor(cmN, s, 64));
        }
        float nmF = fmaxf(mF, cmF);
        float scF = (nmF == mF) ? 1.f : __expf(mF - nmF);
        mF = nmF;
        float nmN = fmaxf(mN, cmN);
        float scN = (nmN == mN) ? 1.f : __expf(mN - nmN);
        mN = nmN;
        float wf0 = __expf(ev0 - mF);
        float wf1 = __expf(ev1 - mF);
        float wn0 = fl0 ? __expf(ev0 - mN) : 0.f;
        float wn1 = fl1 ? __expf(ev1 - mN) : 0.f;
        lF = lF * scF + wf0 + wf1;
        lN = lN * scN + wn0 + wn1;
        float w0 = fl0 ? -wf0 : wf0;
        float w1 = fl1 ? -wf1 : wf1;
        float sNh = __expf(mF - mN);
        aF0 *= scF; aF1 *= scF; aN0 *= scN; aN1 *= scN;
#pragma unroll
        for (int jj = 0; jj < 16; ++jj) {
            float v = __shfl((jj < 8) ? w0 : w1, (lane & 56) | (jj & 7), 64);
            float wf = fabsf(v);
            float wn = (v < 0.f) ? wf * sNh : 0.f;
            aF0 = fmaf(wf, zr[jj].x, aF0);
            aF1 = fmaf(wf, zr[jj].y, aF1);
            aN0 = fmaf(wn, zr[jj].x, aN0);
            aN1 = fmaf(wn, zr[jj].y, aN1);
        }
    }

    // self-loop (in both graphs)
    {
        float e = el[g * NH + hl] + erd;
        e = (e >= 0.f) ? e : 0.2f * e;
        float nmF = fmaxf(mF, e);
        float scF = (nmF == mF) ? 1.f : __expf(mF - nmF);
        lF *= scF; aF0 *= scF; aF1 *= scF; mF = nmF;
        float wf = __expf(e - mF);
        float nmN = fmaxf(mN, e);
        float scN = (nmN == mN) ? 1.f : __expf(mN - nmN);
        lN *= scN; aN0 *= scN; aN1 *= scN; mN = nmN;
        float wn = __expf(e - mN);
        if (j8 == 0) { lF += wf; lN += wn; }
        float2 zv = *(const float2*)(z + (size_t)g * NHD + 2 * lane);
        aF0 = fmaf(wf, zv.x, aF0);
        aF1 = fmaf(wf, zv.y, aF1);
        aN0 = fmaf(wn, zv.x, aN0);
        aN1 = fmaf(wn, zv.y, aN1);
    }

#pragma unroll
    for (int s = 1; s <= 4; s <<= 1) {
        lF += __shfl_xor(lF, s, 64);
        lN += __shfl_xor(lN, s, 64);
    }
    const int c0 = 2 * lane;
    float b0 = bias[c0], b1 = bias[c0 + 1];
    float rF0 = aF0 / lF + b0, rF1 = aF1 / lF + b1;
    float rN0 = aN0 / lN + b0, rN1 = aN1 / lN + b1;
    rF0 = (rF0 >= 0.f) ? rF0 : aslope * rF0;
    rF1 = (rF1 >= 0.f) ? rF1 : aslope * rF1;
    rN0 = (rN0 >= 0.f) ? rN0 : aslope * rN0;
    rN1 = (rN1 >= 0.f) ? rN1 : aslope * rN1;
#pragma unroll
    for (int s = 8; s <= 32; s <<= 1) {
        rF0 += __shfl_xor(rF0, s, 64);
        rF1 += __shfl_xor(rF1, s, 64);
        rN0 += __shfl_xor(rN0, s, 64);
        rN1 += __shfl_xor(rN1, s, 64);
    }
    float hF0 = rF0 * 0.125f, hF1 = rF1 * 0.125f;
    float hN0 = rN0 * 0.125f, hN1 = rN1 * 0.125f;
    if (lane < 8) {
        out[1 + d * ND + 2 * lane] = hF0;
        out[1 + d * ND + 2 * lane + 1] = hF1;
    }
    float num = hF0 * hN0 + hF1 * hN1;
    float na = hF0 * hF0 + hF1 * hF1;
    float nb = hN0 * hN0 + hN1 * hN1;
#pragma unroll
    for (int s = 1; s <= 4; s <<= 1) {
        num += __shfl_xor(num, s, 64);
        na += __shfl_xor(na, s, 64);
        nb += __shfl_xor(nb, s, 64);
    }
    if (lane == 0) {
        float cosv = num / (fmaxf(sqrtf(na), 1e-8f) * fmaxf(sqrtf(nb), 1e-8f));
        sacc[wid] = __expf(cosv / 0.7f);
    }
    __syncthreads();
    if (threadIdx.x == 0) {
        float s = sacc[0] + sacc[1] + sacc[2] + sacc[3];
        atomicAdd(&partial[blockIdx.x & 63], s);
        __threadfence();
        unsigned int r = atomicAdd(donecnt, 1u);
        if (r == NBLK_AGG - 1) {  // last block: finalize loss
            float t = 0.f;
            for (int k = 0; k < 64; ++k)
                t += __hip_atomic_load(&partial[k], __ATOMIC_ACQUIRE,
                                       __HIP_MEMORY_SCOPE_AGENT);
            out[0] = logf(t);
        }
    }
}

extern "C" void kernel_launch(void* const* d_in, const int* in_sizes, int n_in,
                              void* d_out, int out_size, void* d_ws, size_t ws_size,
                              hipStream_t stream) {
    const float* feat = (const float*)d_in[0];
    const float* fc_w = (const float*)d_in[1];
    const float* attn_l = (const float*)d_in[2];
    const float* attn_r = (const float*)d_in[3];
    const float* bias = (const float*)d_in[4];
    const float* prelu_a = (const float*)d_in[5];
    const int* edge_src = (const int*)d_in[6];
    const int* edge_dst = (const int*)d_in[7];
    const int* neg_idx = (const int*)d_in[8];
    float* out = (float*)d_out;

    char* ws = (char*)d_ws;
    unsigned int* donecnt = (unsigned int*)(ws + 0);
    float* partial = (float*)(ws + 64);
    int* count = (int*)(ws + 512);
    int* cursor = (int*)(ws + 80512);
    unsigned char* flag = (unsigned char*)(ws + 160512);
    int* rowstart = (int*)(ws + 480512);
    int* csr = (int*)(ws + 560576);
    float* z = (float*)(ws + 1840576);
    float* el = (float*)(ws + 22320576);
    float* er = (float*)(ws + 23600576);

    hipMemsetAsync(d_ws, 0, 480512, stream);  // ctrl + count + cursor + flag
    k_front<<<dim3(2, 689), 256, 0, stream>>>(feat, fc_w, attn_l, attn_r,
                                              edge_dst, neg_idx, z, el, er,
                                              count, flag);
    k_scan<<<1, 1024, 0, stream>>>(count, rowstart);
    k_scatter<<<(ETOT + 255) / 256, 256, 0, stream>>>(edge_src, edge_dst, flag,
                                                      rowstart, cursor, csr);
    k_agg<<<NBLK_AGG, 256, 0, stream>>>(rowstart, csr, z, el, er, bias, prelu_a,
                                        out, partial, donecnt);
}

// Round 4
// 176.817 us; speedup vs baseline: 1.8292x; 1.8292x over previous
//
#include <hip/hip_runtime.h>

#define NSRC 20000
#define NDST 20000
#define NTOT 40000
#define ETOT 320000
#define ENEG 316800
#define NH 8
#define ND 16
#define NHD 128

// ---------------- workspace layout (bytes) ----------------
// [0, 80000)        count   (20000 int)   } zeroed
// [80000, 160000)   cursor  (20000 int)   } zeroed
// [160000, 480000)  flag    (320000 u8)   } zeroed  -> zero region = 480000 B
// [480000, 560064)  rowstart (20001 int, padded)
// [560064, 1840064) csr (320000 int; bit31 = in-neg-set)
// [1840064, 1920064) expcos (20000 f32)
// [1920064, 22400064) z (40000 x 128 f32)
// [22400064, 23680064) el (40000 x 8 f32)
// [23680064, 24960064) er (40000 x 8 f32)

// GEMM z = feat @ fc_w with fused el/er epilogue; extra blocks do hist+flag.
// Grid (2, 689): by<625 -> gemm tile (64 rows x 64 cols); by>=625 -> 128 blocks
// of edge histogram + neg-flag scatter (independent work, overlapped).
__global__ __launch_bounds__(256) void k_front(const float* __restrict__ A,
                                               const float* __restrict__ B,
                                               const float* __restrict__ attn_l,
                                               const float* __restrict__ attn_r,
                                               const int* __restrict__ edge_dst,
                                               const int* __restrict__ neg_idx,
                                               float* __restrict__ C,
                                               float* __restrict__ el,
                                               float* __restrict__ er,
                                               int* __restrict__ count,
                                               unsigned char* __restrict__ flag) {
    const int tid = threadIdx.x;
    const int bx = blockIdx.x, by = blockIdx.y;
    if (by >= 625) {  // ---- hist + flag blocks ----
        int t0 = ((by - 625) * 2 + bx) * 256 + tid;  // 0..32767
        for (int i = t0; i < ETOT; i += 32768)
            atomicAdd(&count[edge_dst[i] - NSRC], 1);
        for (int i = t0; i < ENEG; i += 32768) flag[neg_idx[i]] = 1;
        return;
    }
    __shared__ float As[16][64];  // [k][m]
    __shared__ float Bs[16][64];  // [k][n]
    const int tx = tid & 15, ty = tid >> 4;
    const int row0 = by * 64 + ty * 4;
    const int col0 = bx * 64 + tx * 4;
    const int lr = tid >> 2, ls = tid & 3;
    const int br = tid >> 4, bs = tid & 15;
    float acc[4][4] = {};
    for (int k0 = 0; k0 < 128; k0 += 16) {
        float4 av = *(const float4*)(A + (by * 64 + lr) * 128 + k0 + ls * 4);
        float4 bv = *(const float4*)(B + (k0 + br) * 128 + bx * 64 + bs * 4);
        __syncthreads();
        As[ls * 4 + 0][lr] = av.x;
        As[ls * 4 + 1][lr] = av.y;
        As[ls * 4 + 2][lr] = av.z;
        As[ls * 4 + 3][lr] = av.w;
        *(float4*)(&Bs[br][bs * 4]) = bv;
        __syncthreads();
#pragma unroll
        for (int k = 0; k < 16; ++k) {
            float4 a = *(const float4*)(&As[k][ty * 4]);
            float4 b = *(const float4*)(&Bs[k][tx * 4]);
            acc[0][0] = fmaf(a.x, b.x, acc[0][0]);
            acc[0][1] = fmaf(a.x, b.y, acc[0][1]);
            acc[0][2] = fmaf(a.x, b.z, acc[0][2]);
            acc[0][3] = fmaf(a.x, b.w, acc[0][3]);
            acc[1][0] = fmaf(a.y, b.x, acc[1][0]);
            acc[1][1] = fmaf(a.y, b.y, acc[1][1]);
            acc[1][2] = fmaf(a.y, b.z, acc[1][2]);
            acc[1][3] = fmaf(a.y, b.w, acc[1][3]);
            acc[2][0] = fmaf(a.z, b.x, acc[2][0]);
            acc[2][1] = fmaf(a.z, b.y, acc[2][1]);
            acc[2][2] = fmaf(a.z, b.z, acc[2][2]);
            acc[2][3] = fmaf(a.z, b.w, acc[2][3]);
            acc[3][0] = fmaf(a.w, b.x, acc[3][0]);
            acc[3][1] = fmaf(a.w, b.y, acc[3][1]);
            acc[3][2] = fmaf(a.w, b.z, acc[3][2]);
            acc[3][3] = fmaf(a.w, b.w, acc[3][3]);
        }
    }
#pragma unroll
    for (int i = 0; i < 4; ++i) {
        *(float4*)(C + (row0 + i) * 128 + col0) =
            make_float4(acc[i][0], acc[i][1], acc[i][2], acc[i][3]);
    }
    // ---- fused el/er epilogue ----
    const int hh = bx * 4 + (tx >> 2);  // head for this thread's 4 cols
    const int q = tx & 3;               // quarter within head
    float4 lv = *(const float4*)(attn_l + hh * ND + q * 4);
    float4 rv = *(const float4*)(attn_r + hh * ND + q * 4);
    float pl[4], pr[4];
#pragma unroll
    for (int i = 0; i < 4; ++i) {
        pl[i] = acc[i][0] * lv.x + acc[i][1] * lv.y + acc[i][2] * lv.z + acc[i][3] * lv.w;
        pr[i] = acc[i][0] * rv.x + acc[i][1] * rv.y + acc[i][2] * rv.z + acc[i][3] * rv.w;
    }
#pragma unroll
    for (int s = 1; s <= 2; s <<= 1) {
#pragma unroll
        for (int i = 0; i < 4; ++i) {
            pl[i] += __shfl_xor(pl[i], s, 64);
            pr[i] += __shfl_xor(pr[i], s, 64);
        }
    }
    if (q == 0) {
#pragma unroll
        for (int i = 0; i < 4; ++i) {
            el[(row0 + i) * NH + hh] = pl[i];
            er[(row0 + i) * NH + hh] = pr[i];
        }
    }
}

// single-block scan: each thread owns 20 contiguous counts, shfl block scan
__global__ __launch_bounds__(1024) void k_scan(const int* __restrict__ count,
                                               int* __restrict__ rowstart) {
    __shared__ int wsum[16];
    const int tid = threadIdx.x;
    const int lane = tid & 63, w = tid >> 6;
    const int base = tid * 20;
    int c[20];
    int s = 0;
#pragma unroll
    for (int k = 0; k < 20; ++k) {
        int i = base + k;
        int v = (i < NDST) ? count[i] : 0;
        c[k] = s;
        s += v;
    }
    int v = s;
    for (int sh = 1; sh < 64; sh <<= 1) {
        int t = __shfl_up(v, sh, 64);
        if (lane >= sh) v += t;
    }
    if (lane == 63) wsum[w] = v;
    __syncthreads();
    int carry = 0;
    for (int ww = 0; ww < w; ++ww) carry += wsum[ww];
    int excl = carry + v - s;
#pragma unroll
    for (int k = 0; k < 20; ++k) {
        int i = base + k;
        if (i < NDST) rowstart[i] = excl + c[k];
    }
    if (tid == 1023) rowstart[NDST] = carry + v;  // = ETOT
}

__global__ __launch_bounds__(256) void k_scatter(const int* __restrict__ edge_src,
                                                 const int* __restrict__ edge_dst,
                                                 const unsigned char* __restrict__ flag,
                                                 const int* __restrict__ rowstart,
                                                 int* __restrict__ cursor,
                                                 int* __restrict__ csr) {
    int i = blockIdx.x * 256 + threadIdx.x;
    if (i >= ETOT) return;
    int d = edge_dst[i] - NSRC;
    int pos = rowstart[d] + atomicAdd(&cursor[d], 1);
    int v = edge_src[i];
    if (flag[i]) v |= (int)0x80000000u;
    csr[pos] = v;
}

// One wave per dst node, chunk = 16 edges, zero LDS.  (round-2 version,
// verbatim — its speed depends on the allocator keeping zr[16] in VGPRs;
// do NOT add LDS/barriers/atomics to this kernel.)
__global__ __launch_bounds__(256) void k_agg(const int* __restrict__ rowstart,
                                             const int* __restrict__ csr,
                                             const float* __restrict__ z,
                                             const float* __restrict__ el,
                                             const float* __restrict__ er,
                                             const float* __restrict__ bias,
                                             const float* __restrict__ prelu_a,
                                             float* __restrict__ out,
                                             float* __restrict__ expcos) {
    const int lane = threadIdx.x & 63;
    const int wid = threadIdx.x >> 6;
    const int d = (blockIdx.x << 2) + wid;  // grid = NDST/4 exactly

    const int g = NSRC + d;
    const int hl = lane >> 3;
    const int j8 = lane & 7;
    const float erd = er[g * NH + hl];
    const float aslope = prelu_a[0];
    const float NEGINF = -__builtin_inff();

    float mF = NEGINF, lF = 0.f, mN = NEGINF, lN = 0.f;
    float aF0 = 0.f, aF1 = 0.f, aN0 = 0.f, aN1 = 0.f;
    const int rs = rowstart[d];
    const int deg = rowstart[d + 1] - rs;

    for (int base = 0; base < deg; base += 16) {
        const int j0 = base + j8, j1 = base + 8 + j8;
        int ent0 = (j0 < deg) ? csr[rs + j0] : g;
        int ent1 = (j1 < deg) ? csr[rs + j1] : g;
        float2 zr[16];
#pragma unroll
        for (int jj = 0; jj < 16; ++jj) {
            int entry = __shfl((jj < 8) ? ent0 : ent1, jj & 7, 64);
            const float* zp = z + (size_t)(entry & 0x7FFFFFFF) * NHD + 2 * lane;
            zr[jj] = *(const float2*)zp;
        }
        float e0 = el[(size_t)(ent0 & 0x7FFFFFFF) * NH + hl] + erd;
        float e1 = el[(size_t)(ent1 & 0x7FFFFFFF) * NH + hl] + erd;
        e0 = (e0 >= 0.f) ? e0 : 0.2f * e0;
        e1 = (e1 >= 0.f) ? e1 : 0.2f * e1;
        float ev0 = (j0 < deg) ? e0 : NEGINF;
        float ev1 = (j1 < deg) ? e1 : NEGINF;
        const int fl0 = (j0 < deg) && (ent0 < 0);
        const int fl1 = (j1 < deg) && (ent1 < 0);
        float cmF = fmaxf(ev0, ev1);
        float cmN = fmaxf(fl0 ? ev0 : NEGINF, fl1 ? ev1 : NEGINF);
#pragma unroll
        for (int s = 1; s <= 4; s <<= 1) {
            cmF = fmaxf(cmF, __shfl_xor(cmF, s, 64));
            cmN = fmaxf(cmN, __shfl_xor(cmN, s, 64));
        }
        float nmF = fmaxf(mF, cmF);
        float scF = (nmF == mF) ? 1.f : __expf(mF - nmF);
        mF = nmF;
        float nmN = fmaxf(mN, cmN);
        float scN = (nmN == mN) ? 1.f : __expf(mN - nmN);
        mN = nmN;
        float wf0 = __expf(ev0 - mF);  // 0 for pad slots (mF finite)
        float wf1 = __expf(ev1 - mF);
        float wn0 = fl0 ? __expf(ev0 - mN) : 0.f;
        float wn1 = fl1 ? __expf(ev1 - mN) : 0.f;
        lF = lF * scF + wf0 + wf1;
        lN = lN * scN + wn0 + wn1;
        float w0 = fl0 ? -wf0 : wf0;  // sign bit = neg-graph membership
        float w1 = fl1 ? -wf1 : wf1;
        float sNh = __expf(mF - mN);  // wf -> wn conversion (per head)
        aF0 *= scF; aF1 *= scF; aN0 *= scN; aN1 *= scN;
#pragma unroll
        for (int jj = 0; jj < 16; ++jj) {
            float v = __shfl((jj < 8) ? w0 : w1, (lane & 56) | (jj & 7), 64);
            float wf = fabsf(v);
            float wn = (v < 0.f) ? wf * sNh : 0.f;
            aF0 = fmaf(wf, zr[jj].x, aF0);
            aF1 = fmaf(wf, zr[jj].y, aF1);
            aN0 = fmaf(wn, zr[jj].x, aN0);
            aN1 = fmaf(wn, zr[jj].y, aN1);
        }
    }

    // self-loop (in both graphs)
    {
        float e = el[g * NH + hl] + erd;
        e = (e >= 0.f) ? e : 0.2f * e;
        float nmF = fmaxf(mF, e);
        float scF = (nmF == mF) ? 1.f : __expf(mF - nmF);
        lF *= scF; aF0 *= scF; aF1 *= scF; mF = nmF;
        float wf = __expf(e - mF);
        float nmN = fmaxf(mN, e);
        float scN = (nmN == mN) ? 1.f : __expf(mN - nmN);
        lN *= scN; aN0 *= scN; aN1 *= scN; mN = nmN;
        float wn = __expf(e - mN);
        if (j8 == 0) { lF += wf; lN += wn; }  // denom: once per head group
        float2 zv = *(const float2*)(z + (size_t)g * NHD + 2 * lane);
        aF0 = fmaf(wf, zv.x, aF0);
        aF1 = fmaf(wf, zv.y, aF1);
        aN0 = fmaf(wn, zv.x, aN0);
        aN1 = fmaf(wn, zv.y, aN1);
    }

    // denominators per head group (reduce over j8 bits)
#pragma unroll
    for (int s = 1; s <= 4; s <<= 1) {
        lF += __shfl_xor(lF, s, 64);
        lN += __shfl_xor(lN, s, 64);
    }
    const int c0 = 2 * lane;
    float b0 = bias[c0], b1 = bias[c0 + 1];
    float rF0 = aF0 / lF + b0, rF1 = aF1 / lF + b1;
    float rN0 = aN0 / lN + b0, rN1 = aN1 / lN + b1;
    rF0 = (rF0 >= 0.f) ? rF0 : aslope * rF0;
    rF1 = (rF1 >= 0.f) ? rF1 : aslope * rF1;
    rN0 = (rN0 >= 0.f) ? rN0 : aslope * rN0;
    rN1 = (rN1 >= 0.f) ? rN1 : aslope * rN1;
    // head mean: sum over heads (bits 3..5), /8
#pragma unroll
    for (int s = 8; s <= 32; s <<= 1) {
        rF0 += __shfl_xor(rF0, s, 64);
        rF1 += __shfl_xor(rF1, s, 64);
        rN0 += __shfl_xor(rN0, s, 64);
        rN1 += __shfl_xor(rN1, s, 64);
    }
    float hF0 = rF0 * 0.125f, hF1 = rF1 * 0.125f;
    float hN0 = rN0 * 0.125f, hN1 = rN1 * 0.125f;
    if (lane < 8) {
        out[1 + d * ND + 2 * lane] = hF0;
        out[1 + d * ND + 2 * lane + 1] = hF1;
    }
    float num = hF0 * hN0 + hF1 * hN1;
    float na = hF0 * hF0 + hF1 * hF1;
    float nb = hN0 * hN0 + hN1 * hN1;
#pragma unroll
    for (int s = 1; s <= 4; s <<= 1) {
        num += __shfl_xor(num, s, 64);
        na += __shfl_xor(na, s, 64);
        nb += __shfl_xor(nb, s, 64);
    }
    if (lane == 0) {
        float cosv = num / (fmaxf(sqrtf(na), 1e-8f) * fmaxf(sqrtf(nb), 1e-8f));
        expcos[d] = __expf(cosv / 0.7f);
    }
}

__global__ __launch_bounds__(1024) void k_loss(const float* __restrict__ expcos,
                                               float* __restrict__ out) {
    __shared__ float sbuf[16];
    float s = 0.f;
    for (int i = threadIdx.x; i < NDST; i += 1024) s += expcos[i];
    for (int sh = 1; sh < 64; sh <<= 1) s += __shfl_xor(s, sh, 64);
    if ((threadIdx.x & 63) == 0) sbuf[threadIdx.x >> 6] = s;
    __syncthreads();
    if (threadIdx.x < 16) {
        float t = sbuf[threadIdx.x];
        for (int sh = 1; sh < 16; sh <<= 1) t += __shfl_xor(t, sh, 16);
        if (threadIdx.x == 0) out[0] = logf(t);
    }
}

extern "C" void kernel_launch(void* const* d_in, const int* in_sizes, int n_in,
                              void* d_out, int out_size, void* d_ws, size_t ws_size,
                              hipStream_t stream) {
    const float* feat = (const float*)d_in[0];
    const float* fc_w = (const float*)d_in[1];
    const float* attn_l = (const float*)d_in[2];
    const float* attn_r = (const float*)d_in[3];
    const float* bias = (const float*)d_in[4];
    const float* prelu_a = (const float*)d_in[5];
    const int* edge_src = (const int*)d_in[6];
    const int* edge_dst = (const int*)d_in[7];
    const int* neg_idx = (const int*)d_in[8];
    float* out = (float*)d_out;

    char* ws = (char*)d_ws;
    int* count = (int*)(ws + 0);
    int* cursor = (int*)(ws + 80000);
    unsigned char* flag = (unsigned char*)(ws + 160000);
    int* rowstart = (int*)(ws + 480000);
    int* csr = (int*)(ws + 560064);
    float* expcos = (float*)(ws + 1840064);
    float* z = (float*)(ws + 1920064);
    float* el = (float*)(ws + 22400064);
    float* er = (float*)(ws + 23680064);

    hipMemsetAsync(d_ws, 0, 480000, stream);  // count + cursor + flag
    k_front<<<dim3(2, 689), 256, 0, stream>>>(feat, fc_w, attn_l, attn_r,
                                              edge_dst, neg_idx, z, el, er,
                                              count, flag);
    k_scan<<<1, 1024, 0, stream>>>(count, rowstart);
    k_scatter<<<(ETOT + 255) / 256, 256, 0, stream>>>(edge_src, edge_dst, flag,
                                                      rowstart, cursor, csr);
    k_agg<<<NDST / 4, 256, 0, stream>>>(rowstart, csr, z, el, er, bias, prelu_a,
                                        out, expcos);
    k_loss<<<1, 1024, 0, stream>>>(expcos, out);
}